// Round 10
// baseline (243.257 us; speedup 1.0000x reference)
//
#include <hip/hip_runtime.h>
#include <hip/hip_bf16.h>

// B=4, T=2048, H=1024, NH=16, HD=64. Inputs FP32, output FP32.
// R19: attn LDS-traffic fix: 64 q-rows/wave (was 32), 4-wave 256-thr blocks.
//  K/V frag reads amortized over 2x q -> per-block-tile LDS traffic
//  192KB -> 128KB (LDS pipe was ~5x oversubscribed vs MFMA: MfmaUtil 21.7%,
//  VALU 34.8%, HBM 26% -- nothing else saturated). Same grid 8x64 = 512
//  blocks = exactly 2/CU; R9 balance map kept; staging bytes unchanged.
//  Mod-64 alignment => wave-active iff kk0 <= wq0; masks only at kk0==wq0.
// gemm (BK=64) / cast_all / epilogue V-transpose unchanged from R18.

typedef unsigned short ushort_t;
typedef __attribute__((ext_vector_type(8))) short  s8v;
typedef __attribute__((ext_vector_type(4))) float  f4v;
typedef __attribute__((ext_vector_type(4))) unsigned int u4v;

__device__ inline ushort_t f2bf(float f) {
    unsigned u = __builtin_bit_cast(unsigned, f);
    u += 0x7fffu + ((u >> 16) & 1u);   // RNE
    return (ushort_t)(u >> 16);
}

// async global->LDS, 16B per lane; LDS dest must be wave-uniform base + lane*16
__device__ inline void gload16(const ushort_t* g, ushort_t* l) {
    __builtin_amdgcn_global_load_lds(
        (const __attribute__((address_space(1))) unsigned int*)g,
        (__attribute__((address_space(3))) unsigned int*)l, 16, 0, 0);
}

// ---------------------------------------------------------------------------
// Fused cast: x (1048576 n8) | wqkv (393216) | wout (131072). 6144 blocks.
// ---------------------------------------------------------------------------
__global__ __launch_bounds__(256) void cast_all(
    const float* __restrict__ x, const float* __restrict__ wqkv,
    const float* __restrict__ wout, ushort_t* __restrict__ xb,
    ushort_t* __restrict__ wqkvb, ushort_t* __restrict__ woutb)
{
    int i = blockIdx.x * 256 + threadIdx.x;      // 0..1572863, exact
    const float* src; ushort_t* dst; int off;
    if (i < 1048576)      { src = x;    dst = xb;    off = i; }
    else if (i < 1441792) { src = wqkv; dst = wqkvb; off = i - 1048576; }
    else                  { src = wout; dst = woutb; off = i - 1441792; }
    const float* p = src + (size_t)off * 8;
    f4v a = *(const f4v*)p;
    f4v b = *(const f4v*)(p + 4);
    union { u4v v; ushort_t u[8]; } o;
    #pragma unroll
    for (int j = 0; j < 4; j++) { o.u[j] = f2bf(a[j]); o.u[j + 4] = f2bf(b[j]); }
    *(u4v*)(dst + (size_t)off * 8) = o.v;
}

// ---------------------------------------------------------------------------
// GEMM C[M,N] = A[M,K]*B[N,K]^T, K=1024, bf16 MFMA, f32 acc. 128^2, BK=64,
// 2-buffer ping-pong, 8-chunk XOR swizzle (phys chunk = logical ^ (row&7)).
// MODE 0: Q scaled + t-major K stores; V tiles transposed+sigma-permuted
//         through LDS in the epilogue (o2 = V^T [b,h,d,sigma(t)]).
// MODE 1: row-major FP32 store.
// ---------------------------------------------------------------------------
template<int MODE>
__global__ __launch_bounds__(256) void gemm_nt(
    const ushort_t* __restrict__ A, const ushort_t* __restrict__ Bm,
    ushort_t* __restrict__ o0, ushort_t* __restrict__ o1, ushort_t* __restrict__ o2,
    float* __restrict__ of)
{
    // main loop: As = SH[buf*8192 .. +8191], Bs = SH[16384 + buf*8192 ..]
    // epilogue (V blocks): Lt[128][68] = SH[0..8703]
    __shared__ __align__(16) ushort_t SH[32768];   // 64 KiB

    const int tid  = threadIdx.x;
    const int m0   = blockIdx.x * 128;
    const int n0   = blockIdx.y * 128;
    const int wave = tid >> 6, lane = tid & 63;
    const int wr = wave >> 1, wc = wave & 1;
    const int lhi = lane >> 4, llo = lane & 15;
    // stage lane map: 8 rows/issue, 8 chunks of 16B per 128B row
    const int sgch = ((lane & 7) ^ (lane >> 3)) * 8;   // pre-swizzled src col

    auto stage = [&](int k0, int buf) {
        #pragma unroll
        for (int p = 0; p < 4; p++) {
            int row = wave * 32 + p * 8 + (lane >> 3);   // 0..127
            gload16(A  + (size_t)(m0 + row) * 1024 + k0 + sgch,
                    &SH[buf * 8192 + row * 64 + (lane & 7) * 8]);
            gload16(Bm + (size_t)(n0 + row) * 1024 + k0 + sgch,
                    &SH[16384 + buf * 8192 + row * 64 + (lane & 7) * 8]);
        }
    };

    f4v acc[4][4] = {};
    int buf = 0;
    const int xs = llo & 7;                    // read-side XOR (row&7 == llo&7)

    stage(0, 0);
    __syncthreads();

    for (int k0 = 0; k0 < 1024; k0 += 64) {
        if (k0 + 64 < 1024) stage(k0 + 64, buf ^ 1);

        #pragma unroll
        for (int s = 0; s < 2; s++) {
            s8v a[4], b[4];
            #pragma unroll
            for (int i = 0; i < 4; i++)
                a[i] = *(const s8v*)&SH[buf * 8192
                        + (wr * 64 + i * 16 + llo) * 64 + ((s * 4 + lhi) ^ xs) * 8];
            #pragma unroll
            for (int i = 0; i < 4; i++)
                b[i] = *(const s8v*)&SH[16384 + buf * 8192
                        + (wc * 64 + i * 16 + llo) * 64 + ((s * 4 + lhi) ^ xs) * 8];
            #pragma unroll
            for (int i = 0; i < 4; i++)
                #pragma unroll
                for (int j = 0; j < 4; j++)
                    acc[i][j] = __builtin_amdgcn_mfma_f32_16x16x32_bf16(a[i], b[j], acc[i][j], 0, 0, 0);
        }

        __syncthreads();
        buf ^= 1;
    }

    if (MODE == 0 && n0 >= 2048) {
        // ---- V tile: transpose + sigma through LDS, coalesced V^T stores ----
        const int hbase = (n0 - 2048) >> 6;      // head base (even)
        const int t0b   = m0 & 2047;
        const int bb    = m0 >> 11;
        #pragma unroll 1
        for (int p = 0; p < 2; p++) {            // t-halves (64 each)
            __syncthreads();                     // LDS free for this pass
            if (wr == p) {
                #pragma unroll
                for (int i = 0; i < 4; i++)
                    #pragma unroll
                    for (int j = 0; j < 4; j++) {
                        union { unsigned long long q; ushort_t u[4]; } w;
                        #pragma unroll
                        for (int r = 0; r < 4; r++) w.u[r] = f2bf(acc[i][j][r]);
                        int nrel = wc * 64 + j * 16 + llo;
                        *(unsigned long long*)&SH[nrel * 68 + i * 16 + lhi * 4] = w.q;
                    }
            }
            __syncthreads();
            #pragma unroll
            for (int cc = 0; cc < 4; cc++) {
                int c  = cc * 256 + tid;         // 0..1023
                int nn = c >> 3, sp0 = (c & 7) * 8;
                union { s8v v; ushort_t u[8]; } o;
                #pragma unroll
                for (int i2 = 0; i2 < 8; i2++) {
                    int sp = sp0 + i2;           // sigma position
                    int k  = ((sp >> 5) << 5) | ((sp & 1) << 4) | ((sp & 31) >> 1);
                    o.u[i2] = SH[nn * 68 + k];
                }
                int head = hbase + (nn >> 6), d = nn & 63;
                size_t bh = (size_t)(bb * 16 + head);
                *(s8v*)(o2 + ((bh * 64 + d) * 2048 + t0b + p * 64 + sp0)) = o.v;
            }
        }
        return;
    }

    #pragma unroll
    for (int i = 0; i < 4; i++) {
        #pragma unroll
        for (int j = 0; j < 4; j++) {
            #pragma unroll
            for (int r = 0; r < 4; r++) {
                int m = m0 + wr * 64 + i * 16 + lhi * 4 + r;
                int n = n0 + wc * 64 + j * 16 + llo;
                if (MODE == 1) {
                    of[(size_t)m * 1024 + n] = acc[i][j][r];
                } else {
                    float val = acc[i][j][r];
                    int b  = m >> 11, t = m & 2047;
                    int which = n >> 10, hh = n & 1023;
                    int head = hh >> 6, d = hh & 63;
                    size_t bh = (size_t)(b * 16 + head);
                    if (which == 0)
                        // Q pre-scaled by 1/sqrt(64)*log2(e) for exp2 softmax
                        o0[(size_t)m * 1024 + hh] = f2bf(val * 0.18033688011112042f);
                    else
                        o1[(bh * 2048 + t) * 64 + d] = f2bf(val);   // K [b,h,t,d]
                }
            }
        }
    }
}

// ---------------------------------------------------------------------------
// Flash attention, causal, exp2 domain, m-free softmax. 256 threads.
// Waves 0,1 -> q-tile p; waves 2,3 -> 15-p. 64 q-rows/wave (4 x 16-row g).
// px = (bh<32) ? x : 7-x balances co-resident block pairs.
// K/V LDS [64][64] XOR-swizzled; P sigma-packed via v_cvt_pk_bf16_f32.
// K/V frags read once per tile, amortized over 4 g (LDS traffic -33%).
// ---------------------------------------------------------------------------
__global__ __launch_bounds__(256, 2) void attn_kernel(
    const ushort_t* __restrict__ q_ws, const ushort_t* __restrict__ k_ws,
    const ushort_t* __restrict__ v_ws, ushort_t* __restrict__ ao_ws)
{
    const int bh   = blockIdx.y;
    const int p    = (bh < 32) ? blockIdx.x : 7 - blockIdx.x;   // balanced pair idx
    const int tid  = threadIdx.x;
    const int wave = tid >> 6, lane = tid & 63;
    const int lhi = lane >> 4, llo = lane & 15;
    const int b = bh >> 4, head = bh & 15;

    const ushort_t* Kb = k_ws + (size_t)bh * 2048 * 64;
    const ushort_t* Vb = v_ws + (size_t)bh * 64 * 2048;   // [d][sigma(t)]

    __shared__ __align__(16) ushort_t Ks [2][4096];       // [buf][64 kk][64 d] swz
    __shared__ __align__(16) ushort_t Vts[2][4096];       // [buf][64 d][64 sig] swz
    __shared__ __align__(16) ushort_t Ps [4][4][1280];    // [wave][g][half][16q][40]

    // stage: 2 K + 2 V issues per lane; row = wave*8 + 32i + (lane>>3)
    const int gch = ((lane & 7) ^ (lane >> 3)) * 8;       // pre-swizzled src col
    auto stage = [&](int t, int buf) {
        const int kk0 = t * 64;
        #pragma unroll
        for (int i = 0; i < 2; i++) {
            int row = wave * 8 + 32 * i + (lane >> 3);    // 0..63
            gload16(Kb + (size_t)(kk0 + row) * 64 + gch,
                    &Ks[buf][(wave * 64 + 256 * i + lane) * 8]);
            gload16(Vb + (size_t)row * 2048 + kk0 + gch,
                    &Vts[buf][(wave * 64 + 256 * i + lane) * 8]);
        }
    };

    const int qt  = (wave >> 1) ? (15 - p) : p;           // this wave's q-tile
    const int wq0 = qt * 128 + (wave & 1) * 64;           // wave's 64 q-rows

    s8v qf[4][2];
    #pragma unroll
    for (int g = 0; g < 4; g++) {
        const ushort_t* Qp = q_ws + (size_t)(b * 2048 + wq0 + g * 16 + llo) * 1024 + head * 64;
        qf[g][0] = *(const s8v*)(Qp + lhi * 8);
        qf[g][1] = *(const s8v*)(Qp + 32 + lhi * 8);
    }

    f4v o[4][4] = {};
    float lsum[4][4] = {};

    const int ntb = 32 - 2 * p;           // shared loop length
    const int xs  = llo & 7;
    int cur = 0;

    stage(0, 0);
    __syncthreads();

    #pragma unroll 1
    for (int t = 0; t < ntb; t++) {
        if (t + 1 < ntb) stage(t + 1, cur ^ 1);

        const int kk0 = t * 64;
        // mod-64 grid: wave-active iff kk0 <= wq0; masks only when kk0 == wq0
        if (kk0 <= wq0) {
            const bool dm = (kk0 == wq0);

            s8v kb[4][2];
            #pragma unroll
            for (int c = 0; c < 4; c++) {
                const int rb = (c * 16 + llo) * 64;
                kb[c][0] = *(const s8v*)&Ks[cur][rb + ((lhi    ) ^ xs) * 8];
                kb[c][1] = *(const s8v*)&Ks[cur][rb + ((4 + lhi) ^ xs) * 8];
            }

            #pragma unroll
            for (int g = 0; g < 4; g++) {
                const int qrb = wq0 + g * 16;
                f4v s[4];
                __builtin_amdgcn_s_setprio(1);
                #pragma unroll
                for (int c = 0; c < 4; c++) {
                    f4v z = {};
                    z = __builtin_amdgcn_mfma_f32_16x16x32_bf16(qf[g][0], kb[c][0], z, 0, 0, 0);
                    z = __builtin_amdgcn_mfma_f32_16x16x32_bf16(qf[g][1], kb[c][1], z, 0, 0, 0);
                    s[c] = z;
                }
                __builtin_amdgcn_s_setprio(0);
                if (dm) {                          // diagonal tile: causal mask
                    #pragma unroll
                    for (int c = 0; c < 4; c++) {
                        int kkg = kk0 + c * 16 + llo;
                        #pragma unroll
                        for (int r = 0; r < 4; r++)
                            if (kkg > qrb + lhi * 4 + r) s[c][r] = -1e9f;
                    }
                }
                #pragma unroll
                for (int h = 0; h < 2; h++) {
                    #pragma unroll
                    for (int r = 0; r < 4; r++) {
                        float p0 = __builtin_amdgcn_exp2f(s[2 * h][r]);
                        float p1 = __builtin_amdgcn_exp2f(s[2 * h + 1][r]);
                        lsum[g][r] += p0 + p1;
                        unsigned pk;
                        asm("v_cvt_pk_bf16_f32 %0, %1, %2" : "=v"(pk) : "v"(p0), "v"(p1));
                        *(unsigned*)&Ps[wave][g][h * 640 + (lhi * 4 + r) * 40 + llo * 2] = pk;
                    }
                }
            }

            s8v vb[4][2];
            #pragma unroll
            for (int cd = 0; cd < 4; cd++) {
                const int rb = (cd * 16 + llo) * 64;
                vb[cd][0] = *(const s8v*)&Vts[cur][rb + ((lhi    ) ^ xs) * 8];
                vb[cd][1] = *(const s8v*)&Vts[cur][rb + ((4 + lhi) ^ xs) * 8];
            }
            #pragma unroll
            for (int g = 0; g < 4; g++) {
                s8v pa0 = *(const s8v*)&Ps[wave][g][llo * 40 + lhi * 8];
                s8v pa1 = *(const s8v*)&Ps[wave][g][640 + llo * 40 + lhi * 8];
                __builtin_amdgcn_s_setprio(1);
                #pragma unroll
                for (int cd = 0; cd < 4; cd++) {
                    o[g][cd] = __builtin_amdgcn_mfma_f32_16x16x32_bf16(pa0, vb[cd][0], o[g][cd], 0, 0, 0);
                    o[g][cd] = __builtin_amdgcn_mfma_f32_16x16x32_bf16(pa1, vb[cd][1], o[g][cd], 0, 0, 0);
                }
                __builtin_amdgcn_s_setprio(0);
            }
        }

        __syncthreads();
        cur ^= 1;
    }

    // final l-sum reduction across the 16-lane llo group
    #pragma unroll
    for (int off = 1; off < 16; off <<= 1)
        #pragma unroll
        for (int g = 0; g < 4; g++)
            #pragma unroll
            for (int r = 0; r < 4; r++)
                lsum[g][r] += __shfl_xor(lsum[g][r], off, 64);

    #pragma unroll
    for (int g = 0; g < 4; g++)
        #pragma unroll
        for (int cd = 0; cd < 4; cd++)
            #pragma unroll
            for (int r = 0; r < 4; r++) {
                int qq = wq0 + g * 16 + lhi * 4 + r;
                int d  = cd * 16 + llo;
                ao_ws[((size_t)(b * 2048 + qq)) * 1024 + head * 64 + d] =
                    f2bf(o[g][cd][r] / lsum[g][r]);
            }
}

// ---------------------------------------------------------------------------
extern "C" void kernel_launch(void* const* d_in, const int* in_sizes, int n_in,
                              void* d_out, int out_size, void* d_ws, size_t ws_size,
                              hipStream_t stream) {
    const float* x    = (const float*)d_in[0];
    const float* wqkv = (const float*)d_in[1];
    const float* wout = (const float*)d_in[2];

    // ws (bf16 elems): wqkvb 3M | woutb 1M | xb 8M | q 8M | k 8M | v^T 8M = 72 MB
    // ao <- xb (dead after gemm0); V^T written directly by gemm0 epilogue.
    ushort_t* wqkvb = (ushort_t*)d_ws;
    ushort_t* woutb = wqkvb + 3145728;
    ushort_t* xb    = woutb + 1048576;
    ushort_t* q_ws  = xb + 8388608;
    ushort_t* k_ws  = q_ws + 8388608;
    ushort_t* v_ws  = k_ws + 8388608;     // V^T [b,h,d,sigma(t)]
    ushort_t* ao_ws = xb;                 // attn output
    float*    out   = (float*)d_out;

    cast_all<<<6144, 256, 0, stream>>>(x, wqkv, wout, xb, wqkvb, woutb);
    gemm_nt<0><<<dim3(64, 24), 256, 0, stream>>>(xb, wqkvb, q_ws, k_ws, v_ws, nullptr);
    attn_kernel<<<dim3(8, 64), 256, 0, stream>>>(q_ws, k_ws, v_ws, ao_ws);
    gemm_nt<1><<<dim3(64, 8), 256, 0, stream>>>(ao_ws, woutb, nullptr, nullptr, nullptr, out);
}

// Round 12
// 227.232 us; speedup vs baseline: 1.0705x; 1.0705x over previous
//
#include <hip/hip_runtime.h>
#include <hip/hip_bf16.h>

// B=4, T=2048, H=1024, NH=16, HD=64. Inputs FP32, output FP32.
// R21 = R20 with the causal-mask gate FIXED:
//  R20 masked the diagonal only when kk0+63 > wq0+15 (last key vs LAST row),
//  leaving the wq0-kk0==48 diagonal waves unmasked -> absmax 0.557 fail.
//  Correct gate: mask whenever kk0+63 > wq0 (max key vs MIN row).
// Structure (unchanged from R20): attn = 16 waves x 16 q-rows (1024 thr),
//  grid 8x64 = 512 = 2 blocks/CU -> 32 waves/CU (8/SIMD, full occupancy);
//  staging waves 0-7 K / 8-15 V (1 gload each); sigma-pack, XOR swizzle,
//  balance map px=(bh<32)?x:7-x, setprio, m-free exp2 softmax.
// gemm (BK=64) / cast_all / epilogue V-transpose unchanged from R18.

typedef unsigned short ushort_t;
typedef __attribute__((ext_vector_type(8))) short  s8v;
typedef __attribute__((ext_vector_type(4))) float  f4v;
typedef __attribute__((ext_vector_type(4))) unsigned int u4v;

__device__ inline ushort_t f2bf(float f) {
    unsigned u = __builtin_bit_cast(unsigned, f);
    u += 0x7fffu + ((u >> 16) & 1u);   // RNE
    return (ushort_t)(u >> 16);
}

// async global->LDS, 16B per lane; LDS dest must be wave-uniform base + lane*16
__device__ inline void gload16(const ushort_t* g, ushort_t* l) {
    __builtin_amdgcn_global_load_lds(
        (const __attribute__((address_space(1))) unsigned int*)g,
        (__attribute__((address_space(3))) unsigned int*)l, 16, 0, 0);
}

// ---------------------------------------------------------------------------
// Fused cast: x (1048576 n8) | wqkv (393216) | wout (131072). 6144 blocks.
// ---------------------------------------------------------------------------
__global__ __launch_bounds__(256) void cast_all(
    const float* __restrict__ x, const float* __restrict__ wqkv,
    const float* __restrict__ wout, ushort_t* __restrict__ xb,
    ushort_t* __restrict__ wqkvb, ushort_t* __restrict__ woutb)
{
    int i = blockIdx.x * 256 + threadIdx.x;      // 0..1572863, exact
    const float* src; ushort_t* dst; int off;
    if (i < 1048576)      { src = x;    dst = xb;    off = i; }
    else if (i < 1441792) { src = wqkv; dst = wqkvb; off = i - 1048576; }
    else                  { src = wout; dst = woutb; off = i - 1441792; }
    const float* p = src + (size_t)off * 8;
    f4v a = *(const f4v*)p;
    f4v b = *(const f4v*)(p + 4);
    union { u4v v; ushort_t u[8]; } o;
    #pragma unroll
    for (int j = 0; j < 4; j++) { o.u[j] = f2bf(a[j]); o.u[j + 4] = f2bf(b[j]); }
    *(u4v*)(dst + (size_t)off * 8) = o.v;
}

// ---------------------------------------------------------------------------
// GEMM C[M,N] = A[M,K]*B[N,K]^T, K=1024, bf16 MFMA, f32 acc. 128^2, BK=64,
// 2-buffer ping-pong, 8-chunk XOR swizzle (phys chunk = logical ^ (row&7)).
// MODE 0: Q scaled + t-major K stores; V tiles transposed+sigma-permuted
//         through LDS in the epilogue (o2 = V^T [b,h,d,sigma(t)]).
// MODE 1: row-major FP32 store.
// ---------------------------------------------------------------------------
template<int MODE>
__global__ __launch_bounds__(256) void gemm_nt(
    const ushort_t* __restrict__ A, const ushort_t* __restrict__ Bm,
    ushort_t* __restrict__ o0, ushort_t* __restrict__ o1, ushort_t* __restrict__ o2,
    float* __restrict__ of)
{
    // main loop: As = SH[buf*8192 .. +8191], Bs = SH[16384 + buf*8192 ..]
    // epilogue (V blocks): Lt[128][68] = SH[0..8703]
    __shared__ __align__(16) ushort_t SH[32768];   // 64 KiB

    const int tid  = threadIdx.x;
    const int m0   = blockIdx.x * 128;
    const int n0   = blockIdx.y * 128;
    const int wave = tid >> 6, lane = tid & 63;
    const int wr = wave >> 1, wc = wave & 1;
    const int lhi = lane >> 4, llo = lane & 15;
    // stage lane map: 8 rows/issue, 8 chunks of 16B per 128B row
    const int sgch = ((lane & 7) ^ (lane >> 3)) * 8;   // pre-swizzled src col

    auto stage = [&](int k0, int buf) {
        #pragma unroll
        for (int p = 0; p < 4; p++) {
            int row = wave * 32 + p * 8 + (lane >> 3);   // 0..127
            gload16(A  + (size_t)(m0 + row) * 1024 + k0 + sgch,
                    &SH[buf * 8192 + row * 64 + (lane & 7) * 8]);
            gload16(Bm + (size_t)(n0 + row) * 1024 + k0 + sgch,
                    &SH[16384 + buf * 8192 + row * 64 + (lane & 7) * 8]);
        }
    };

    f4v acc[4][4] = {};
    int buf = 0;
    const int xs = llo & 7;                    // read-side XOR (row&7 == llo&7)

    stage(0, 0);
    __syncthreads();

    for (int k0 = 0; k0 < 1024; k0 += 64) {
        if (k0 + 64 < 1024) stage(k0 + 64, buf ^ 1);

        #pragma unroll
        for (int s = 0; s < 2; s++) {
            s8v a[4], b[4];
            #pragma unroll
            for (int i = 0; i < 4; i++)
                a[i] = *(const s8v*)&SH[buf * 8192
                        + (wr * 64 + i * 16 + llo) * 64 + ((s * 4 + lhi) ^ xs) * 8];
            #pragma unroll
            for (int i = 0; i < 4; i++)
                b[i] = *(const s8v*)&SH[16384 + buf * 8192
                        + (wc * 64 + i * 16 + llo) * 64 + ((s * 4 + lhi) ^ xs) * 8];
            #pragma unroll
            for (int i = 0; i < 4; i++)
                #pragma unroll
                for (int j = 0; j < 4; j++)
                    acc[i][j] = __builtin_amdgcn_mfma_f32_16x16x32_bf16(a[i], b[j], acc[i][j], 0, 0, 0);
        }

        __syncthreads();
        buf ^= 1;
    }

    if (MODE == 0 && n0 >= 2048) {
        // ---- V tile: transpose + sigma through LDS, coalesced V^T stores ----
        const int hbase = (n0 - 2048) >> 6;      // head base (even)
        const int t0b   = m0 & 2047;
        const int bb    = m0 >> 11;
        #pragma unroll 1
        for (int p = 0; p < 2; p++) {            // t-halves (64 each)
            __syncthreads();                     // LDS free for this pass
            if (wr == p) {
                #pragma unroll
                for (int i = 0; i < 4; i++)
                    #pragma unroll
                    for (int j = 0; j < 4; j++) {
                        union { unsigned long long q; ushort_t u[4]; } w;
                        #pragma unroll
                        for (int r = 0; r < 4; r++) w.u[r] = f2bf(acc[i][j][r]);
                        int nrel = wc * 64 + j * 16 + llo;
                        *(unsigned long long*)&SH[nrel * 68 + i * 16 + lhi * 4] = w.q;
                    }
            }
            __syncthreads();
            #pragma unroll
            for (int cc = 0; cc < 4; cc++) {
                int c  = cc * 256 + tid;         // 0..1023
                int nn = c >> 3, sp0 = (c & 7) * 8;
                union { s8v v; ushort_t u[8]; } o;
                #pragma unroll
                for (int i2 = 0; i2 < 8; i2++) {
                    int sp = sp0 + i2;           // sigma position
                    int k  = ((sp >> 5) << 5) | ((sp & 1) << 4) | ((sp & 31) >> 1);
                    o.u[i2] = SH[nn * 68 + k];
                }
                int head = hbase + (nn >> 6), d = nn & 63;
                size_t bh = (size_t)(bb * 16 + head);
                *(s8v*)(o2 + ((bh * 64 + d) * 2048 + t0b + p * 64 + sp0)) = o.v;
            }
        }
        return;
    }

    #pragma unroll
    for (int i = 0; i < 4; i++) {
        #pragma unroll
        for (int j = 0; j < 4; j++) {
            #pragma unroll
            for (int r = 0; r < 4; r++) {
                int m = m0 + wr * 64 + i * 16 + lhi * 4 + r;
                int n = n0 + wc * 64 + j * 16 + llo;
                if (MODE == 1) {
                    of[(size_t)m * 1024 + n] = acc[i][j][r];
                } else {
                    float val = acc[i][j][r];
                    int b  = m >> 11, t = m & 2047;
                    int which = n >> 10, hh = n & 1023;
                    int head = hh >> 6, d = hh & 63;
                    size_t bh = (size_t)(b * 16 + head);
                    if (which == 0)
                        // Q pre-scaled by 1/sqrt(64)*log2(e) for exp2 softmax
                        o0[(size_t)m * 1024 + hh] = f2bf(val * 0.18033688011112042f);
                    else
                        o1[(bh * 2048 + t) * 64 + d] = f2bf(val);   // K [b,h,t,d]
                }
            }
        }
    }
}

// ---------------------------------------------------------------------------
// Flash attention, causal, exp2 domain, m-free softmax. 1024 threads.
// Waves 0-7 -> q-tile p (16 rows each); waves 8-15 -> 15-p.
// px = (bh<32) ? x : 7-x balances co-resident block pairs.
// Staging: wave w<8 stages K chunk w; w>=8 stages V chunk w-8 (1 gload ea).
// K/V LDS [64][64] XOR-swizzled; P sigma-packed via v_cvt_pk_bf16_f32.
// 2 blocks/CU x 16 waves = 32 waves/CU (8/SIMD, full occupancy).
// ---------------------------------------------------------------------------
__global__ __launch_bounds__(1024, 8) void attn_kernel(
    const ushort_t* __restrict__ q_ws, const ushort_t* __restrict__ k_ws,
    const ushort_t* __restrict__ v_ws, ushort_t* __restrict__ ao_ws)
{
    const int bh   = blockIdx.y;
    const int p    = (bh < 32) ? blockIdx.x : 7 - blockIdx.x;   // balanced pair idx
    const int tid  = threadIdx.x;
    const int wave = tid >> 6, lane = tid & 63;
    const int half = wave >> 3, wsub = wave & 7;
    const int lhi = lane >> 4, llo = lane & 15;
    const int b = bh >> 4, head = bh & 15;

    const ushort_t* Kb = k_ws + (size_t)bh * 2048 * 64;
    const ushort_t* Vb = v_ws + (size_t)bh * 64 * 2048;   // [d][sigma(t)]

    __shared__ __align__(16) ushort_t Ks [2][4096];       // [buf][64 kk][64 d] swz
    __shared__ __align__(16) ushort_t Vts[2][4096];       // [buf][64 d][64 sig] swz
    __shared__ __align__(16) ushort_t Ps [16][1280];      // [wave][half][16q][40]

    // stage: wave w<8 -> K chunk wsub; w>=8 -> V chunk wsub. 1 gload/wave.
    const int gch = ((lane & 7) ^ (lane >> 3)) * 8;       // pre-swizzled src col
    auto stage = [&](int t, int buf) {
        const int kk0 = t * 64;
        const int row = wsub * 8 + (lane >> 3);           // 0..63
        if (half == 0)
            gload16(Kb + (size_t)(kk0 + row) * 64 + gch,
                    &Ks[buf][(wsub * 64 + lane) * 8]);
        else
            gload16(Vb + (size_t)row * 2048 + kk0 + gch,
                    &Vts[buf][(wsub * 64 + lane) * 8]);
    };

    const int qt  = half ? (15 - p) : p;                  // this wave's q-tile
    const int wq0 = qt * 128 + wsub * 16;                 // wave's 16 q-rows

    s8v qf0, qf1;
    {
        const ushort_t* Qp = q_ws + (size_t)(b * 2048 + wq0 + llo) * 1024 + head * 64;
        qf0 = *(const s8v*)(Qp + lhi * 8);
        qf1 = *(const s8v*)(Qp + 32 + lhi * 8);
    }

    f4v o[4] = {};
    float lsum[4] = {};

    const int ntb = 32 - 2 * p;           // shared loop length
    const int xs  = llo & 7;
    int cur = 0;

    stage(0, 0);
    __syncthreads();

    #pragma unroll 1
    for (int t = 0; t < ntb; t++) {
        if (t + 1 < ntb) stage(t + 1, cur ^ 1);

        const int kk0 = t * 64;
        if (kk0 <= wq0 + 15) {            // wave has unmasked keys this tile
            f4v s[4];
            __builtin_amdgcn_s_setprio(1);
            #pragma unroll
            for (int c = 0; c < 4; c++) {
                const int rb = (c * 16 + llo) * 64;
                s8v kb0 = *(const s8v*)&Ks[cur][rb + ((lhi    ) ^ xs) * 8];
                s8v kb1 = *(const s8v*)&Ks[cur][rb + ((4 + lhi) ^ xs) * 8];
                f4v z = {};
                z = __builtin_amdgcn_mfma_f32_16x16x32_bf16(qf0, kb0, z, 0, 0, 0);
                z = __builtin_amdgcn_mfma_f32_16x16x32_bf16(qf1, kb1, z, 0, 0, 0);
                s[c] = z;
            }
            __builtin_amdgcn_s_setprio(0);

            if (kk0 + 63 > wq0) {         // diagonal tile: causal mask
                                          // (max key vs MIN row -- R20 bugfix)
                #pragma unroll
                for (int c = 0; c < 4; c++) {
                    int kkg = kk0 + c * 16 + llo;
                    #pragma unroll
                    for (int r = 0; r < 4; r++)
                        if (kkg > wq0 + lhi * 4 + r) s[c][r] = -1e9f;
                }
            }
            #pragma unroll
            for (int h = 0; h < 2; h++) {
                #pragma unroll
                for (int r = 0; r < 4; r++) {
                    float p0 = __builtin_amdgcn_exp2f(s[2 * h][r]);
                    float p1 = __builtin_amdgcn_exp2f(s[2 * h + 1][r]);
                    lsum[r] += p0 + p1;
                    unsigned pk;
                    asm("v_cvt_pk_bf16_f32 %0, %1, %2" : "=v"(pk) : "v"(p0), "v"(p1));
                    *(unsigned*)&Ps[wave][h * 640 + (lhi * 4 + r) * 40 + llo * 2] = pk;
                }
            }

            s8v pa0 = *(const s8v*)&Ps[wave][llo * 40 + lhi * 8];
            s8v pa1 = *(const s8v*)&Ps[wave][640 + llo * 40 + lhi * 8];
            __builtin_amdgcn_s_setprio(1);
            #pragma unroll
            for (int cd = 0; cd < 4; cd++) {
                const int rb = (cd * 16 + llo) * 64;
                s8v vb0 = *(const s8v*)&Vts[cur][rb + ((lhi    ) ^ xs) * 8];
                s8v vb1 = *(const s8v*)&Vts[cur][rb + ((4 + lhi) ^ xs) * 8];
                o[cd] = __builtin_amdgcn_mfma_f32_16x16x32_bf16(pa0, vb0, o[cd], 0, 0, 0);
                o[cd] = __builtin_amdgcn_mfma_f32_16x16x32_bf16(pa1, vb1, o[cd], 0, 0, 0);
            }
            __builtin_amdgcn_s_setprio(0);
        }

        __syncthreads();
        cur ^= 1;
    }

    // final l-sum reduction across the 16-lane llo group
    #pragma unroll
    for (int off = 1; off < 16; off <<= 1)
        #pragma unroll
        for (int r = 0; r < 4; r++)
            lsum[r] += __shfl_xor(lsum[r], off, 64);

    #pragma unroll
    for (int cd = 0; cd < 4; cd++)
        #pragma unroll
        for (int r = 0; r < 4; r++) {
            int qq = wq0 + lhi * 4 + r;
            int d  = cd * 16 + llo;
            ao_ws[((size_t)(b * 2048 + qq)) * 1024 + head * 64 + d] =
                f2bf(o[cd][r] / lsum[r]);
        }
}

// ---------------------------------------------------------------------------
extern "C" void kernel_launch(void* const* d_in, const int* in_sizes, int n_in,
                              void* d_out, int out_size, void* d_ws, size_t ws_size,
                              hipStream_t stream) {
    const float* x    = (const float*)d_in[0];
    const float* wqkv = (const float*)d_in[1];
    const float* wout = (const float*)d_in[2];

    // ws (bf16 elems): wqkvb 3M | woutb 1M | xb 8M | q 8M | k 8M | v^T 8M = 72 MB
    // ao <- xb (dead after gemm0); V^T written directly by gemm0 epilogue.
    ushort_t* wqkvb = (ushort_t*)d_ws;
    ushort_t* woutb = wqkvb + 3145728;
    ushort_t* xb    = woutb + 1048576;
    ushort_t* q_ws  = xb + 8388608;
    ushort_t* k_ws  = q_ws + 8388608;
    ushort_t* v_ws  = k_ws + 8388608;     // V^T [b,h,d,sigma(t)]
    ushort_t* ao_ws = xb;                 // attn output
    float*    out   = (float*)d_out;

    cast_all<<<6144, 256, 0, stream>>>(x, wqkv, wout, xb, wqkvb, woutb);
    gemm_nt<0><<<dim3(64, 24), 256, 0, stream>>>(xb, wqkvb, q_ws, k_ws, v_ws, nullptr);
    attn_kernel<<<dim3(8, 64), 1024, 0, stream>>>(q_ws, k_ws, v_ws, ao_ws);
    gemm_nt<1><<<dim3(64, 8), 256, 0, stream>>>(ao_ws, woutb, nullptr, nullptr, nullptr, out);
}